// Round 12
// baseline (94.083 us; speedup 1.0000x reference)
//
#include <hip/hip_runtime.h>
#include <hip/hip_fp16.h>

#define P 10
#define D 1024
#define NROWS 16384

typedef float nfloat4 __attribute__((ext_vector_type(4)));   // clang-native for nontemporal builtins

// ---------------------------------------------------------------------------
// Column mapping (r4 keeper):
//   k = e_hi*256 + lane*4 + e_lo,  e = e_hi*4 + e_lo,  e in [0,16), lane in [0,64)
//   stage j flips bit j of k:
//     j=0,1 -> e bits 0,1 (intra) | j=2..7 -> lane bit j-2 (cross-lane) | j=8,9 -> e bits 2,3 (intra)
// Coef table swizzled: ctab[j*D + e*64 + lane] = coefs for column k(e,lane),
// stored as 4 x f16 (8 B). psi folded into stage-9 coefs. (r10 keeper)
//
// Cross-lane exchanges: masks 1,2 via DPP quad_perm; masks 16,32 via gfx950
// permlane16/32_swap (VALU); masks 4,8 via __shfl_xor (ds_swizzle).
// FIX vs r11: permlane select orientation was inverted. Correct derivation:
// the swap exchanges ODD rows of vdst with EVEN rows of src, so with both
// inputs = x, p[0] holds x^MASK on ODD rows, p[1] on EVEN rows.
// ---------------------------------------------------------------------------
__global__ void coef_kernel(const float* __restrict__ theta,
                            const float* __restrict__ phi,
                            const float* __restrict__ psi,
                            uint2* __restrict__ ctab) {
    int idx = blockIdx.x * blockDim.x + threadIdx.x;
    if (idx >= P * D) return;
    int j = idx >> 10;
    int slot = idx & (D - 1);
    int e = slot >> 6;
    int lane = slot & 63;
    int k = ((e >> 2) << 8) + (lane << 2) + (e & 3);   // column this slot serves
    int b = (k >> j) & 1;
    unsigned lowmask = (1u << j) - 1u;
    unsigned m = ((unsigned)k & lowmask) | (((unsigned)k >> 1) & ~lowmask); // delete bit j
    float th = theta[j * (D / 2) + m];
    float ph = phi[j * (D / 2) + m];
    float h = th * 0.5f;
    float s1 = sinf(h), c1 = cosf(h);
    float s2 = sinf(h + ph), c2 = cosf(h + ph);
    float ur, ui, vr, vi;
    if (b) { ur =  s1 * s1; vr = -c1 * s2; ui = -c1 * s1; vi = c1 * c2; }
    else   { ur = -s1 * s2; vr = -c1 * s1; ui =  s1 * c2; vi = c1 * c1; }
    if (j == P - 1) {
        float ps = psi[k];
        float cp = cosf(ps), sp = sinf(ps);
        float ur2 = cp * ur - sp * ui, ui2 = sp * ur + cp * ui;
        float vr2 = cp * vr - sp * vi, vi2 = sp * vr + cp * vi;
        ur = ur2; ui = ui2; vr = vr2; vi = vi2;
    }
    __half2 uh = __floats2half2_rn(ur, ui);
    __half2 vh = __floats2half2_rn(vr, vi);
    uint2 w;
    w.x = *reinterpret_cast<unsigned int*>(&uh);
    w.y = *reinterpret_cast<unsigned int*>(&vh);
    ctab[idx] = w;
}

__device__ __forceinline__ void unpack_c(uint2 w, float& ur, float& ui,
                                         float& vr, float& vi) {
    __half2 a = *reinterpret_cast<__half2*>(&w.x);
    __half2 b = *reinterpret_cast<__half2*>(&w.y);
    ur = __low2float(a); ui = __high2float(a);
    vr = __low2float(b); vi = __high2float(b);
}

// ---------------------------------------------------------------------------
// Cross-lane XOR exchange, pipe-optimized per mask.
// ---------------------------------------------------------------------------
template <int CTRL>
__device__ __forceinline__ float xdpp(float x) {
    return __uint_as_float((unsigned)__builtin_amdgcn_update_dpp(
        0, (int)__float_as_uint(x), CTRL, 0xF, 0xF, true));
}

template <int MODE>
__device__ __forceinline__ float lane_xor(float x, int lane) {
    if constexpr (MODE == 1) {
        return xdpp<0xB1>(x);                    // quad_perm [1,0,3,2]
    } else if constexpr (MODE == 2) {
        return xdpp<0x4E>(x);                    // quad_perm [2,3,0,1]
    }
#if __has_builtin(__builtin_amdgcn_permlane16_swap)
    else if constexpr (MODE == 16) {
        unsigned u = __float_as_uint(x);
        auto p = __builtin_amdgcn_permlane16_swap(u, u, false, false);
        // p[0] holds partner on ODD 16-rows, p[1] on EVEN 16-rows
        return __uint_as_float((((lane >> 4) & 1) != 0) ? p[0] : p[1]);
    }
#endif
#if __has_builtin(__builtin_amdgcn_permlane32_swap)
    else if constexpr (MODE == 32) {
        unsigned u = __float_as_uint(x);
        auto p = __builtin_amdgcn_permlane32_swap(u, u, false, false);
        // p[0] holds partner on the UPPER 32 lanes, p[1] on the LOWER 32
        return __uint_as_float((lane >= 32) ? p[0] : p[1]);
    }
#endif
    else {
        return __shfl_xor(x, MODE);
    }
}

// ---------------------------------------------------------------------------
// Intra-thread butterfly stage: partner differs in a bit of e (mask PM).
// ---------------------------------------------------------------------------
template <int PM>
__device__ __forceinline__ void stage_intra(float (&ra)[16], float (&ia)[16],
                                            float (&rb)[16], float (&ib)[16],
                                            const uint2* cj) {
#pragma unroll
    for (int e0 = 0; e0 < 16; ++e0) {
        if (e0 & PM) continue;
        const int e1 = e0 | PM;
        uint2 w0 = cj[e0 * 64];
        uint2 w1 = cj[e1 * 64];
        float u0r, u0i, v0r, v0i, u1r, u1i, v1r, v1i;
        unpack_c(w0, u0r, u0i, v0r, v0i);
        unpack_c(w1, u1r, u1i, v1r, v1i);
        float ar0 = ra[e0], ai0 = ia[e0], ar1 = ra[e1], ai1 = ia[e1];
        float br0 = rb[e0], bi0 = ib[e0], br1 = rb[e1], bi1 = ib[e1];
        ra[e0] = u0r * ar0 - u0i * ai0 + v0r * ar1 - v0i * ai1;
        ia[e0] = u0r * ai0 + u0i * ar0 + v0r * ai1 + v0i * ar1;
        ra[e1] = u1r * ar1 - u1i * ai1 + v1r * ar0 - v1i * ai0;
        ia[e1] = u1r * ai1 + u1i * ar1 + v1r * ai0 + v1i * ar0;
        rb[e0] = u0r * br0 - u0i * bi0 + v0r * br1 - v0i * bi1;
        ib[e0] = u0r * bi0 + u0i * br0 + v0r * bi1 + v0i * br1;
        rb[e1] = u1r * br1 - u1i * bi1 + v1r * br0 - v1i * bi0;
        ib[e1] = u1r * bi1 + u1i * br1 + v1r * bi0 + v1i * br0;
    }
}

// ---------------------------------------------------------------------------
// Cross-lane butterfly stage: partner differs in lane bit MASK.
// ---------------------------------------------------------------------------
template <int MASK>
__device__ __forceinline__ void stage_x(float (&ra)[16], float (&ia)[16],
                                        float (&rb)[16], float (&ib)[16],
                                        const uint2* cj, int lane) {
#pragma unroll
    for (int e = 0; e < 16; ++e) {
        uint2 w = cj[e * 64];
        float ur, ui, vr, vi;
        unpack_c(w, ur, ui, vr, vi);
        float sra = lane_xor<MASK>(ra[e], lane);
        float sia = lane_xor<MASK>(ia[e], lane);
        float srb = lane_xor<MASK>(rb[e], lane);
        float sib = lane_xor<MASK>(ib[e], lane);
        float nra = ur * ra[e] - ui * ia[e] + vr * sra - vi * sia;
        float nia = ur * ia[e] + ui * ra[e] + vr * sia + vi * sra;
        float nrb = ur * rb[e] - ui * ib[e] + vr * srb - vi * sib;
        float nib = ur * ib[e] + ui * rb[e] + vr * sib + vi * srb;
        ra[e] = nra; ia[e] = nia; rb[e] = nrb; ib[e] = nib;
    }
}

__global__ __launch_bounds__(256) void fft_kernel(const float* __restrict__ X,
                                                  const uint2* __restrict__ ctab,
                                                  float* __restrict__ out) {
    const int lane = threadIdx.x & 63;
    const int wave = threadIdx.x >> 6;
    const long rowbase = (long)blockIdx.x * 8 + (long)wave * 2;
    const float* x0 = X + rowbase * 2048 + lane * 4;
    const float* x1 = x0 + 2048;
    const uint2* cb = ctab + lane;

    float ra[16], ia[16], rb[16], ib[16];
#pragma unroll
    for (int eh = 0; eh < 4; ++eh) {
        float4 v0r = *(const float4*)(x0 + eh * 256);
        float4 v0i = *(const float4*)(x0 + 1024 + eh * 256);
        float4 v1r = *(const float4*)(x1 + eh * 256);
        float4 v1i = *(const float4*)(x1 + 1024 + eh * 256);
        ra[eh * 4 + 0] = v0r.x; ra[eh * 4 + 1] = v0r.y; ra[eh * 4 + 2] = v0r.z; ra[eh * 4 + 3] = v0r.w;
        ia[eh * 4 + 0] = v0i.x; ia[eh * 4 + 1] = v0i.y; ia[eh * 4 + 2] = v0i.z; ia[eh * 4 + 3] = v0i.w;
        rb[eh * 4 + 0] = v1r.x; rb[eh * 4 + 1] = v1r.y; rb[eh * 4 + 2] = v1r.z; rb[eh * 4 + 3] = v1r.w;
        ib[eh * 4 + 0] = v1i.x; ib[eh * 4 + 1] = v1i.y; ib[eh * 4 + 2] = v1i.z; ib[eh * 4 + 3] = v1i.w;
    }

    stage_intra<1>(ra, ia, rb, ib, cb + 0 * D);
    stage_intra<2>(ra, ia, rb, ib, cb + 1 * D);

    stage_x<1>(ra, ia, rb, ib, cb + 2 * D, lane);    // DPP quad_perm
    stage_x<2>(ra, ia, rb, ib, cb + 3 * D, lane);    // DPP quad_perm
    stage_x<4>(ra, ia, rb, ib, cb + 4 * D, lane);    // ds_swizzle
    stage_x<8>(ra, ia, rb, ib, cb + 5 * D, lane);    // ds_swizzle
    stage_x<16>(ra, ia, rb, ib, cb + 6 * D, lane);   // permlane16_swap
    stage_x<32>(ra, ia, rb, ib, cb + 7 * D, lane);   // permlane32_swap

    stage_intra<4>(ra, ia, rb, ib, cb + 8 * D);
    stage_intra<8>(ra, ia, rb, ib, cb + 9 * D);

    float* o0 = out + rowbase * 2048 + lane * 4;
    float* o1 = o0 + 2048;
#pragma unroll
    for (int eh = 0; eh < 4; ++eh) {
        nfloat4 v0r = { ra[eh * 4 + 0], ra[eh * 4 + 1], ra[eh * 4 + 2], ra[eh * 4 + 3] };
        nfloat4 v0i = { ia[eh * 4 + 0], ia[eh * 4 + 1], ia[eh * 4 + 2], ia[eh * 4 + 3] };
        nfloat4 v1r = { rb[eh * 4 + 0], rb[eh * 4 + 1], rb[eh * 4 + 2], rb[eh * 4 + 3] };
        nfloat4 v1i = { ib[eh * 4 + 0], ib[eh * 4 + 1], ib[eh * 4 + 2], ib[eh * 4 + 3] };
        __builtin_nontemporal_store(v0r, (nfloat4*)(o0 + eh * 256));
        __builtin_nontemporal_store(v0i, (nfloat4*)(o0 + 1024 + eh * 256));
        __builtin_nontemporal_store(v1r, (nfloat4*)(o1 + eh * 256));
        __builtin_nontemporal_store(v1i, (nfloat4*)(o1 + 1024 + eh * 256));
    }
}

extern "C" void kernel_launch(void* const* d_in, const int* in_sizes, int n_in,
                              void* d_out, int out_size, void* d_ws, size_t ws_size,
                              hipStream_t stream) {
    const float* X     = (const float*)d_in[0];
    const float* theta = (const float*)d_in[1];
    const float* phi   = (const float*)d_in[2];
    const float* psi   = (const float*)d_in[3];
    uint2* ctab = (uint2*)d_ws;   // P*D*8 B = 80 KB

    coef_kernel<<<(P * D + 255) / 256, 256, 0, stream>>>(theta, phi, psi, ctab);
    fft_kernel<<<NROWS / 8, 256, 0, stream>>>(X, ctab, (float*)d_out);
}

// Round 13
// 75.492 us; speedup vs baseline: 1.2463x; 1.2463x over previous
//
#include <hip/hip_runtime.h>
#include <hip/hip_fp16.h>

#define P 10
#define D 1024
#define NROWS 16384

typedef float nfloat4 __attribute__((ext_vector_type(4)));   // clang-native for nontemporal builtins

// ---------------------------------------------------------------------------
// Column mapping (r4 keeper):
//   k = e_hi*256 + lane*4 + e_lo,  e = e_hi*4 + e_lo,  e in [0,16), lane in [0,64)
//   stage j flips bit j of k:
//     j=0,1 -> e bits 0,1 (intra) | j=2..7 -> lane bit j-2 (shfl) | j=8,9 -> e bits 2,3 (intra)
//
// THIS ROUND (only change vs r10): PAIR-PACKED f16 coef table.
//   ctab[j*512 + p*64 + lane] = uint4 {h2(uA), h2(vA), h2(uB), h2(vB)}
// where (eA,eB) is the stage's butterfly pair p:
//   intra stages (0,1,8,9): eA = insert-0-at-bit(p, log2(PM)), eB = eA|PM
//   shfl  stages (2..7):    eA = 2p, eB = 2p+1  (two butterflies bundled)
// One coalesced dwordx4 per pair: VMEM instrs 160 -> 80 per thread, same
// bytes, same FMA count, same chain depth. psi folded into stage-9 coefs.
// All cross-lane exchanges are __shfl_xor (r12 permlane/DPP regressed).
// ---------------------------------------------------------------------------
__device__ __forceinline__ float4 coef_uv(int j, int e, int lane,
                                          const float* __restrict__ theta,
                                          const float* __restrict__ phi,
                                          const float* __restrict__ psi) {
    int k = ((e >> 2) << 8) | (lane << 2) | (e & 3);
    int b = (k >> j) & 1;
    unsigned lowmask = (1u << j) - 1u;
    unsigned m = ((unsigned)k & lowmask) | (((unsigned)k >> 1) & ~lowmask); // delete bit j
    float th = theta[j * (D / 2) + m];
    float ph = phi[j * (D / 2) + m];
    float h = th * 0.5f;
    float s1 = sinf(h), c1 = cosf(h);
    float s2 = sinf(h + ph), c2 = cosf(h + ph);
    float ur, ui, vr, vi;
    if (b) { ur =  s1 * s1; vr = -c1 * s2; ui = -c1 * s1; vi = c1 * c2; }
    else   { ur = -s1 * s2; vr = -c1 * s1; ui =  s1 * c2; vi = c1 * c1; }
    if (j == P - 1) {
        float ps = psi[k];
        float cp = cosf(ps), sp = sinf(ps);
        float ur2 = cp * ur - sp * ui, ui2 = sp * ur + cp * ui;
        float vr2 = cp * vr - sp * vi, vi2 = sp * vr + cp * vi;
        ur = ur2; ui = ui2; vr = vr2; vi = vi2;
    }
    return make_float4(ur, ui, vr, vi);
}

__device__ __forceinline__ unsigned packh2(float x, float y) {
    __half2 h = __floats2half2_rn(x, y);
    return *reinterpret_cast<unsigned*>(&h);
}

__global__ void coef_kernel(const float* __restrict__ theta,
                            const float* __restrict__ phi,
                            const float* __restrict__ psi,
                            uint4* __restrict__ ctab) {
    int idx = blockIdx.x * blockDim.x + threadIdx.x;
    if (idx >= P * 512) return;
    int j = idx >> 9;
    int slot = idx & 511;
    int p = slot >> 6;
    int lane = slot & 63;
    int eA, eB;
    if (j >= 2 && j <= 7) {                 // shfl stage: bundle (2p, 2p+1)
        eA = 2 * p; eB = 2 * p + 1;
    } else {                                // intra stage: butterfly pair
        int PM = (j == 0) ? 1 : (j == 1) ? 2 : (j == 8) ? 4 : 8;
        eA = (p & (PM - 1)) | ((p & ~(PM - 1)) << 1);
        eB = eA | PM;
    }
    float4 a = coef_uv(j, eA, lane, theta, phi, psi);
    float4 b = coef_uv(j, eB, lane, theta, phi, psi);
    uint4 w;
    w.x = packh2(a.x, a.y);
    w.y = packh2(a.z, a.w);
    w.z = packh2(b.x, b.y);
    w.w = packh2(b.z, b.w);
    ctab[idx] = w;
}

__device__ __forceinline__ void unp2(unsigned u, float& x, float& y) {
    __half2 h = *reinterpret_cast<__half2*>(&u);
    x = __low2float(h); y = __high2float(h);
}

// ---------------------------------------------------------------------------
// Intra-thread butterfly stage: partner differs in bit PM of e.
// One dwordx4 load per butterfly pair.
// ---------------------------------------------------------------------------
template <int PM>
__device__ __forceinline__ void stage_intra(float (&ra)[16], float (&ia)[16],
                                            float (&rb)[16], float (&ib)[16],
                                            const uint4* cj) {
#pragma unroll
    for (int e0 = 0; e0 < 16; ++e0) {
        if (e0 & PM) continue;
        const int e1 = e0 | PM;
        const int p = (e0 & (PM - 1)) | ((e0 >> 1) & ~(PM - 1));  // delete bit log2(PM)
        uint4 w = cj[p * 64];
        float u0r, u0i, v0r, v0i, u1r, u1i, v1r, v1i;
        unp2(w.x, u0r, u0i); unp2(w.y, v0r, v0i);
        unp2(w.z, u1r, u1i); unp2(w.w, v1r, v1i);
        float ar0 = ra[e0], ai0 = ia[e0], ar1 = ra[e1], ai1 = ia[e1];
        float br0 = rb[e0], bi0 = ib[e0], br1 = rb[e1], bi1 = ib[e1];
        ra[e0] = u0r * ar0 - u0i * ai0 + v0r * ar1 - v0i * ai1;
        ia[e0] = u0r * ai0 + u0i * ar0 + v0r * ai1 + v0i * ar1;
        ra[e1] = u1r * ar1 - u1i * ai1 + v1r * ar0 - v1i * ai0;
        ia[e1] = u1r * ai1 + u1i * ar1 + v1r * ai0 + v1i * ar0;
        rb[e0] = u0r * br0 - u0i * bi0 + v0r * br1 - v0i * bi1;
        ib[e0] = u0r * bi0 + u0i * br0 + v0r * bi1 + v0i * br1;
        rb[e1] = u1r * br1 - u1i * bi1 + v1r * br0 - v1i * bi0;
        ib[e1] = u1r * bi1 + u1i * br1 + v1r * bi0 + v1i * br0;
    }
}

// ---------------------------------------------------------------------------
// Cross-lane butterfly stage: partner differs in lane bit MASK.
// One dwordx4 load covers e = 2p and 2p+1.
// ---------------------------------------------------------------------------
template <int MASK>
__device__ __forceinline__ void stage_shfl(float (&ra)[16], float (&ia)[16],
                                           float (&rb)[16], float (&ib)[16],
                                           const uint4* cj) {
#pragma unroll
    for (int p = 0; p < 8; ++p) {
        uint4 w = cj[p * 64];
#pragma unroll
        for (int h = 0; h < 2; ++h) {
            const int e = 2 * p + h;
            float ur, ui, vr, vi;
            unp2(h == 0 ? w.x : w.z, ur, ui);
            unp2(h == 0 ? w.y : w.w, vr, vi);
            float sra = __shfl_xor(ra[e], MASK);
            float sia = __shfl_xor(ia[e], MASK);
            float srb = __shfl_xor(rb[e], MASK);
            float sib = __shfl_xor(ib[e], MASK);
            float nra = ur * ra[e] - ui * ia[e] + vr * sra - vi * sia;
            float nia = ur * ia[e] + ui * ra[e] + vr * sia + vi * sra;
            float nrb = ur * rb[e] - ui * ib[e] + vr * srb - vi * sib;
            float nib = ur * ib[e] + ui * rb[e] + vr * sib + vi * srb;
            ra[e] = nra; ia[e] = nia; rb[e] = nrb; ib[e] = nib;
        }
    }
}

__global__ __launch_bounds__(256) void fft_kernel(const float* __restrict__ X,
                                                  const uint4* __restrict__ ctab,
                                                  float* __restrict__ out) {
    const int lane = threadIdx.x & 63;
    const int wave = threadIdx.x >> 6;
    const long rowbase = (long)blockIdx.x * 8 + (long)wave * 2;
    const float* x0 = X + rowbase * 2048 + lane * 4;
    const float* x1 = x0 + 2048;
    const uint4* cb = ctab + lane;

    float ra[16], ia[16], rb[16], ib[16];
#pragma unroll
    for (int eh = 0; eh < 4; ++eh) {
        float4 v0r = *(const float4*)(x0 + eh * 256);
        float4 v0i = *(const float4*)(x0 + 1024 + eh * 256);
        float4 v1r = *(const float4*)(x1 + eh * 256);
        float4 v1i = *(const float4*)(x1 + 1024 + eh * 256);
        ra[eh * 4 + 0] = v0r.x; ra[eh * 4 + 1] = v0r.y; ra[eh * 4 + 2] = v0r.z; ra[eh * 4 + 3] = v0r.w;
        ia[eh * 4 + 0] = v0i.x; ia[eh * 4 + 1] = v0i.y; ia[eh * 4 + 2] = v0i.z; ia[eh * 4 + 3] = v0i.w;
        rb[eh * 4 + 0] = v1r.x; rb[eh * 4 + 1] = v1r.y; rb[eh * 4 + 2] = v1r.z; rb[eh * 4 + 3] = v1r.w;
        ib[eh * 4 + 0] = v1i.x; ib[eh * 4 + 1] = v1i.y; ib[eh * 4 + 2] = v1i.z; ib[eh * 4 + 3] = v1i.w;
    }

    stage_intra<1>(ra, ia, rb, ib, cb + 0 * 512);
    stage_intra<2>(ra, ia, rb, ib, cb + 1 * 512);

    stage_shfl<1>(ra, ia, rb, ib, cb + 2 * 512);
    stage_shfl<2>(ra, ia, rb, ib, cb + 3 * 512);
    stage_shfl<4>(ra, ia, rb, ib, cb + 4 * 512);
    stage_shfl<8>(ra, ia, rb, ib, cb + 5 * 512);
    stage_shfl<16>(ra, ia, rb, ib, cb + 6 * 512);
    stage_shfl<32>(ra, ia, rb, ib, cb + 7 * 512);

    stage_intra<4>(ra, ia, rb, ib, cb + 8 * 512);
    stage_intra<8>(ra, ia, rb, ib, cb + 9 * 512);

    float* o0 = out + rowbase * 2048 + lane * 4;
    float* o1 = o0 + 2048;
#pragma unroll
    for (int eh = 0; eh < 4; ++eh) {
        nfloat4 v0r = { ra[eh * 4 + 0], ra[eh * 4 + 1], ra[eh * 4 + 2], ra[eh * 4 + 3] };
        nfloat4 v0i = { ia[eh * 4 + 0], ia[eh * 4 + 1], ia[eh * 4 + 2], ia[eh * 4 + 3] };
        nfloat4 v1r = { rb[eh * 4 + 0], rb[eh * 4 + 1], rb[eh * 4 + 2], rb[eh * 4 + 3] };
        nfloat4 v1i = { ib[eh * 4 + 0], ib[eh * 4 + 1], ib[eh * 4 + 2], ib[eh * 4 + 3] };
        __builtin_nontemporal_store(v0r, (nfloat4*)(o0 + eh * 256));
        __builtin_nontemporal_store(v0i, (nfloat4*)(o0 + 1024 + eh * 256));
        __builtin_nontemporal_store(v1r, (nfloat4*)(o1 + eh * 256));
        __builtin_nontemporal_store(v1i, (nfloat4*)(o1 + 1024 + eh * 256));
    }
}

extern "C" void kernel_launch(void* const* d_in, const int* in_sizes, int n_in,
                              void* d_out, int out_size, void* d_ws, size_t ws_size,
                              hipStream_t stream) {
    const float* X     = (const float*)d_in[0];
    const float* theta = (const float*)d_in[1];
    const float* phi   = (const float*)d_in[2];
    const float* psi   = (const float*)d_in[3];
    uint4* ctab = (uint4*)d_ws;   // P*512*16 B = 80 KB

    coef_kernel<<<(P * 512 + 255) / 256, 256, 0, stream>>>(theta, phi, psi, ctab);
    fft_kernel<<<NROWS / 8, 256, 0, stream>>>(X, ctab, (float*)d_out);
}